// Round 1
// baseline (932.468 us; speedup 1.0000x reference)
//
#include <hip/hip_runtime.h>
#include <hip/hip_bf16.h>
#include <math.h>

#define N_NODES 10000
#define N_EDGES 320000
#define DIM     128
#define NLAYERS 5
#define CHIDN   20
#define BNEPS   1e-5f
#define TOPK    100

__device__ __forceinline__ float sigmoidf_(float x){ return 1.0f/(1.0f + expf(-x)); }

// ---------------- init: zero accumulators ----------------
__global__ void k_init(int* counts, float* gamma, float* delta_f, float* dg, float* gfd,
                       double* wh_acc, double* kapsum, double* lossacc)
{
  int i = blockIdx.x*blockDim.x + threadIdx.x;
  int stride = gridDim.x*blockDim.x;
  for (int j=i; j<N_NODES; j+=stride){ counts[j]=0; gamma[j]=0.f; delta_f[j]=0.f; dg[j]=0.f; gfd[j]=0.f; }
  if (i < 64){ wh_acc[i]=0.0; kapsum[i]=0.0; }
  if (i == 64) lossacc[0]=0.0;
}

// ---------------- node embed + kappa/f MLPs ----------------
__global__ __launch_bounds__(256) void k_node(
  const int* __restrict__ xf, const float* __restrict__ atom_emb,
  const float* __restrict__ cw1, const float* __restrict__ cb1,
  const float* __restrict__ cw2, const float* __restrict__ cb2,
  const float* __restrict__ fw1, const float* __restrict__ fb1,
  const float* __restrict__ fw2, const float* __restrict__ fb2,
  float* __restrict__ x_out, float* __restrict__ node_rep,
  float* __restrict__ kap, float* __restrict__ fv, double* __restrict__ kapsum)
{
  __shared__ float scw1[DIM*CHIDN];
  __shared__ float sfw1[DIM*CHIDN];
  __shared__ float sx[4][DIM];
  __shared__ float sred[4][64];
  int tid = threadIdx.x;
  for (int i=tid;i<DIM*CHIDN;i+=256){ scw1[i]=cw1[i]; sfw1[i]=fw1[i]; }
  int wid = tid>>6, lane = tid&63;
  int n = blockIdx.x*4 + wid;     // N_NODES = 4*2500 exactly, no tail
  const float* e0 = atom_emb;
  const float* e1 = atom_emb + 128*DIM;
  int f0 = xf[n*2+0], f1 = xf[n*2+1];
  float2 a = *(const float2*)(e0 + f0*DIM + lane*2);
  float2 b = *(const float2*)(e1 + f1*DIM + lane*2);
  float2 xv; xv.x = a.x+b.x; xv.y = a.y+b.y;
  *(float2*)(x_out + (size_t)n*DIM + lane*2) = xv;
  *(float2*)(node_rep + (size_t)n*DIM + lane*2) = xv;
  sx[wid][lane*2] = xv.x; sx[wid][lane*2+1] = xv.y;
  __syncthreads();
  if (lane < CHIDN) {
    float acc = cb1[lane];
    for (int d=0; d<DIM; ++d) acc = fmaf(sx[wid][d], scw1[d*CHIDN+lane], acc);
    sred[wid][lane] = fmaxf(acc, 0.f) * cw2[lane];
  } else if (lane >= 32 && lane < 32+CHIDN) {
    int hh = lane-32;
    float acc = fb1[hh];
    for (int d=0; d<DIM; ++d) acc = fmaf(sx[wid][d], sfw1[d*CHIDN+hh], acc);
    sred[wid][32+hh] = fmaxf(acc, 0.f) * fw2[hh];
  }
  __syncthreads();
  if (lane == 0) {
    float s = cb2[0];
    for (int h=0;h<CHIDN;++h) s += sred[wid][h];
    float kp = sigmoidf_(s);
    kap[n] = kp;
    sred[wid][62] = kp;
  } else if (lane == 1) {
    float s = fb2[0];
    for (int h=0;h<CHIDN;++h) s += sred[wid][32+h];
    fv[n] = sigmoidf_(s);
  }
  __syncthreads();
  if (tid == 0) {
    double ks = (double)sred[0][62] + (double)sred[1][62] + (double)sred[2][62] + (double)sred[3][62];
    atomicAdd(&kapsum[blockIdx.x & 63], ks);
  }
}

// ---------------- edge pre: in-degree counts + ea@wm_w1 reduction ----------------
__global__ __launch_bounds__(256) void k_edge_pre(
  const int* __restrict__ ei, const int* __restrict__ eattr,
  const float* __restrict__ w1, int* __restrict__ counts, double* __restrict__ wh_acc)
{
  __shared__ float part_[4][64];
  int tid = threadIdx.x;
  int wid = tid>>6, lane = tid&63;
  float acc = 0.f;
  int gw = blockIdx.x*4+wid, nw = gridDim.x*4;
  for (int bb=gw; bb<N_EDGES/64; bb+=nw) {
    int e = bb*64 + lane;
    int a0=eattr[e*3], a1=eattr[e*3+1], a2=eattr[e*3+2];
    float ea = (float)(a0+a1+a2);
    int dst = ei[N_EDGES+e];
    atomicAdd(&counts[dst], 1);
    const float* wrow = w1 + (size_t)bb*64*64;
    #pragma unroll 8
    for (int t=0;t<64;++t) {
      float eat = __shfl(ea, t);
      acc = fmaf(eat, wrow[t*64 + lane], acc);
    }
  }
  part_[wid][lane] = acc;
  __syncthreads();
  if (tid < 64) {
    float s = part_[0][tid]+part_[1][tid]+part_[2][tid]+part_[3][tid];
    atomicAdd(&wh_acc[tid], (double)s);
  }
}

// ---------------- exact top-100 of kappa via radix-select ----------------
__global__ __launch_bounds__(1024) void k_topk(const float* __restrict__ kap, int* __restrict__ mask)
{
  __shared__ int hist[256];
  __shared__ int sbuf[1024];
  __shared__ unsigned s_prefix;
  __shared__ int s_krem;
  int tid = threadIdx.x;
  unsigned prefix = 0; int krem = TOPK;
  for (int pass=3; pass>=0; --pass) {
    if (tid<256) hist[tid]=0;
    __syncthreads();
    int shift = pass*8;
    unsigned hi_mask = (pass==3) ? 0u : (0xFFFFFFFFu << (shift+8));
    for (int i=tid;i<N_NODES;i+=1024) {
      unsigned b = __float_as_uint(kap[i]);
      if ((b & hi_mask) == (prefix & hi_mask))
        atomicAdd(&hist[(b>>shift)&255], 1);
    }
    __syncthreads();
    if (tid==0) {
      int c=0; int b=255;
      for (; b>0; --b){ int h=hist[b]; if (c+h >= krem) break; c+=h; }
      s_prefix = prefix | ((unsigned)b << shift);
      s_krem = krem - c;
    }
    __syncthreads();
    prefix = s_prefix; krem = s_krem;
    __syncthreads();
  }
  unsigned thr = prefix;
  const int per = 10; // 1024*10 >= 10000
  int base = tid*per;
  int cnt = 0;
  for (int i=base; i<base+per && i<N_NODES; ++i)
    if (__float_as_uint(kap[i])==thr) cnt++;
  sbuf[tid]=cnt; __syncthreads();
  for (int off=1; off<1024; off<<=1){
    int t = (tid>=off)? sbuf[tid-off] : 0;
    __syncthreads();
    sbuf[tid] += t;
    __syncthreads();
  }
  int taken = sbuf[tid] - cnt; // exclusive prefix in index order
  for (int i=base; i<base+per && i<N_NODES; ++i) {
    unsigned b = __float_as_uint(kap[i]);
    int sel;
    if (b > thr) sel = 1;
    else if (b == thr) { sel = (taken < krem) ? 1 : 0; taken++; }
    else sel = 0;
    mask[i] = sel;
  }
}

// ---------------- exclusive scan of counts -> offs; zero cursor ----------------
__global__ __launch_bounds__(1024) void k_scan(const int* __restrict__ counts,
                                               int* __restrict__ offs, int* __restrict__ cursor)
{
  __shared__ int buf[1024];
  int tid = threadIdx.x;
  int run = 0;
  for (int chunk=0; chunk<10; ++chunk) {
    int i = chunk*1024 + tid;
    int v = (i<N_NODES)? counts[i] : 0;
    buf[tid]=v; __syncthreads();
    for (int off=1; off<1024; off<<=1){
      int t = (tid>=off)? buf[tid-off]:0;
      __syncthreads();
      buf[tid]+=t;
      __syncthreads();
    }
    if (i<N_NODES){ offs[i+1] = run + buf[tid]; cursor[i]=0; }
    run += buf[1023];
    __syncthreads();
  }
  if (tid==0) offs[0]=0;
}

// ---------------- hidden layers of the edge-weight MLP ----------------
__global__ void k_wmlp2(const double* __restrict__ wh_acc, const float* __restrict__ wb1,
                        const float* __restrict__ w2m, const float* __restrict__ wb2,
                        float* __restrict__ wh2)
{
  __shared__ float h1[64];
  int tid = threadIdx.x;
  h1[tid] = fmaxf((float)wh_acc[tid] + wb1[tid], 0.f);
  __syncthreads();
  float acc = wb2[tid];
  for (int k=0;k<64;++k) acc = fmaf(h1[k], w2m[k*64+tid], acc);
  wh2[tid] = fmaxf(acc, 0.f);
}

// ---------------- per-edge: weights, gamma/delta_f, CSR fill ----------------
__global__ __launch_bounds__(256) void k_edge_main(
  const int* __restrict__ ei, const int* __restrict__ eattr,
  const float* __restrict__ nev, const float* __restrict__ w3,
  const float* __restrict__ wb3, const float* __restrict__ wh2,
  const float* __restrict__ fv, const int* __restrict__ mask,
  const int* __restrict__ offs, int* __restrict__ cursor,
  float* __restrict__ weights, float* __restrict__ gamma, float* __restrict__ delta_f,
  int* __restrict__ csr_src, int* __restrict__ csr_attr,
  float* __restrict__ csr_w0, float* __restrict__ csr_w1)
{
  __shared__ float w2[64];
  if (threadIdx.x < 64) w2[threadIdx.x] = wh2[threadIdx.x];
  __syncthreads();
  int stride = gridDim.x*blockDim.x;
  for (int e = blockIdx.x*blockDim.x + threadIdx.x; e < N_EDGES; e += stride) {
    float ws = wb3[e];
    #pragma unroll 16
    for (int h=0; h<64; ++h) ws = fmaf(w2[h], w3[(size_t)h*N_EDGES + e], ws);
    float wt = sigmoidf_(ws);
    weights[e] = wt;
    int s = ei[e], d = ei[N_EDGES + e];
    float fd = fv[d] - fv[s];
    atomicAdd(&gamma[s], 0.5f*wt*fd*fd);
    atomicAdd(&delta_f[s], wt*fd);
    int a0 = eattr[e*3], a1 = eattr[e*3+1], a2 = eattr[e*3+2];
    float ew = nev[e];
    float mew = (mask[s] | mask[d]) ? 1e-5f : 1.0f;
    int pos = offs[d] + atomicAdd(&cursor[d], 1);
    csr_src[pos]  = s;
    csr_attr[pos] = a0 | (a1<<8) | (a2<<16);
    csr_w0[pos]   = ew;
    csr_w1[pos]   = mew*ew;
  }
}

// ---------------- second curvature pass ----------------
__global__ void k_edge2(const int* __restrict__ ei, const float* __restrict__ weights,
                        const float* __restrict__ fv, const float* __restrict__ gamma,
                        const float* __restrict__ delta_f,
                        float* __restrict__ dg, float* __restrict__ gfd)
{
  int stride = gridDim.x*blockDim.x;
  for (int e = blockIdx.x*blockDim.x + threadIdx.x; e < N_EDGES; e += stride) {
    int s = ei[e], d = ei[N_EDGES+e];
    float wt = weights[e];
    atomicAdd(&dg[s], wt*(gamma[d]-gamma[s]));
    float fd = fv[d]-fv[s];
    atomicAdd(&gfd[s], wt*fd*(delta_f[d]-delta_f[s]));
  }
}

// ---------------- N x N curvature loss (kappa outer-product broadcast) ----------------
__global__ __launch_bounds__(256) void k_loss(
  const float* __restrict__ kap, const float* __restrict__ gamma,
  const float* __restrict__ dg, const float* __restrict__ gfd,
  double* __restrict__ lossacc)
{
  __shared__ float skap[N_NODES];
  __shared__ double dred[256];
  int tid = threadIdx.x;
  for (int i=tid;i<N_NODES;i+=256) skap[i]=kap[i];
  __syncthreads();
  int lane = tid & 63, part = tid >> 6;
  int j = blockIdx.x*64 + lane;
  float g=0.f, g2=0.f;
  bool valid = j < N_NODES;
  if (valid){ g = gamma[j]; g2 = 0.5f*(dg[j]-gfd[j]); }
  float sum = 0.f;
  if (valid) {
    int i0 = part*2500, i1 = i0+2500;
    for (int i=i0;i<i1;++i) sum += fmaxf(fmaf(skap[i], g, -g2), 0.f);
  }
  dred[tid] = (double)sum;
  __syncthreads();
  for (int off=128; off>0; off>>=1){
    if (tid<off) dred[tid]+=dred[tid+off];
    __syncthreads();
  }
  if (tid==0) atomicAdd(lossacc, dred[0]);
}

__global__ void k_finalize(const double* __restrict__ lossacc, const double* __restrict__ kapsum,
                           float* __restrict__ out)
{
  if (threadIdx.x==0 && blockIdx.x==0){
    double ks = 0;
    for (int i=0;i<64;++i) ks += kapsum[i];
    out[N_NODES*DIM] = (float)(lossacc[0] - ks);
  }
}

// ---------------- per-layer: CSR aggregation + self-loop ----------------
__global__ __launch_bounds__(256) void k_aggr(
  const float* __restrict__ hprev, const int* __restrict__ offs,
  const int* __restrict__ csr_src, const int* __restrict__ csr_attr,
  const float* __restrict__ csr_w,
  const float* __restrict__ bond,       // already offset to layer l (3*16*128 floats)
  const float* __restrict__ nsl, const float* __restrict__ conv_eps, int l,
  float* __restrict__ hpre, double* __restrict__ stats_l)
{
  __shared__ float tab[3*16*DIM];       // 24 KB
  int tid = threadIdx.x;
  for (int i=tid; i<3*16*DIM; i+=256) tab[i] = bond[i];
  if (blockIdx.x == 0) {
    for (int i=tid; i<512; i+=256) stats_l[i] = 0.0;   // zero this layer's BN stat accumulators
  }
  __syncthreads();
  int wid = tid>>6, lane = tid&63;
  int n = blockIdx.x*4 + wid;
  float eps = conv_eps[l];
  int beg = offs[n], end = offs[n+1];
  float c = eps * nsl[n];
  float2 h0 = *(const float2*)(hprev + (size_t)n*DIM + lane*2);
  float ax = c*h0.x, ay = c*h0.y;
  for (int j0=beg; j0<end; j0+=64) {
    int m = end - j0; if (m>64) m=64;
    int s=0, at=0; float w=0.f;
    if (lane < m) { s = csr_src[j0+lane]; at = csr_attr[j0+lane]; w = csr_w[j0+lane]; }
    for (int t=0;t<m;++t) {
      int st = __shfl(s, t);
      int a  = __shfl(at, t);
      float wt = __shfl(w, t);
      const float2 hs = *(const float2*)(hprev + (size_t)st*DIM + lane*2);
      int a0 = a&255, a1=(a>>8)&255, a2=(a>>16)&255;
      float2 e0 = *(const float2*)(tab + a0*DIM + lane*2);
      float2 e1 = *(const float2*)(tab + 16*DIM + a1*DIM + lane*2);
      float2 e2 = *(const float2*)(tab + 32*DIM + a2*DIM + lane*2);
      float vx = hs.x + e0.x + e1.x + e2.x;
      float vy = hs.y + e0.y + e1.y + e2.y;
      ax = fmaf(wt, fmaxf(vx,0.f), ax);
      ay = fmaf(wt, fmaxf(vy,0.f), ay);
    }
  }
  float2 o; o.x=ax; o.y=ay;
  *(float2*)(hpre + (size_t)n*DIM + lane*2) = o;
}

// ---------------- 10000x128 @ 128x128 GEMM, optional fused BN+relu on input,
//                  fused column-stat (sum, sumsq) epilogue ----------------
__global__ __launch_bounds__(256) void k_gemm(
  const float* __restrict__ A, const float* __restrict__ W,
  const float* __restrict__ bias, float* __restrict__ Out,
  const double* __restrict__ statsIn, const float* __restrict__ gin, const float* __restrict__ bin,
  double* __restrict__ statsOut, int useBnIn)
{
  __shared__ __align__(16) float Ws[DIM*DIM];   // 64 KB
  __shared__ __align__(16) float As[64*DIM];    // 32 KB (reused as reduction scratch)
  __shared__ float s_scale[DIM], s_shift[DIM];
  int tid = threadIdx.x;
  if (useBnIn && tid < DIM) {
    double m = statsIn[tid] * (1.0/N_NODES);
    double v = statsIn[DIM+tid] * (1.0/N_NODES) - m*m;
    float inv = (float)(1.0 / sqrt(v + (double)BNEPS));
    float sc = gin[tid]*inv;
    s_scale[tid] = sc;
    s_shift[tid] = bin[tid] - (float)m*sc;
  }
  for (int i=tid; i<DIM*DIM/4; i+=256) ((float4*)Ws)[i] = ((const float4*)W)[i];
  __syncthreads();
  int r0 = blockIdx.x*64;
  for (int i=tid; i<64*DIM/4; i+=256) {
    int r = r0 + (i>>5);
    int c4 = (i&31);
    float4 v;
    if (r < N_NODES) v = ((const float4*)A)[(size_t)r*32 + c4];
    else { v.x=0;v.y=0;v.z=0;v.w=0; }
    if (useBnIn) {
      int c = c4*4;
      v.x = fmaxf(fmaf(v.x, s_scale[c+0], s_shift[c+0]), 0.f);
      v.y = fmaxf(fmaf(v.y, s_scale[c+1], s_shift[c+1]), 0.f);
      v.z = fmaxf(fmaf(v.z, s_scale[c+2], s_shift[c+2]), 0.f);
      v.w = fmaxf(fmaf(v.w, s_scale[c+3], s_shift[c+3]), 0.f);
    }
    ((float4*)As)[i] = v;
  }
  __syncthreads();
  int tc = tid & 31, tr = tid >> 5;
  float acc[8][4];
  #pragma unroll
  for (int i=0;i<8;++i){ acc[i][0]=0.f; acc[i][1]=0.f; acc[i][2]=0.f; acc[i][3]=0.f; }
  #pragma unroll 4
  for (int k=0;k<DIM;++k) {
    float4 wv = *(const float4*)&Ws[k*DIM + tc*4];
    #pragma unroll
    for (int i=0;i<8;++i) {
      float a = As[(tr*8+i)*DIM + k];
      acc[i][0] = fmaf(a, wv.x, acc[i][0]);
      acc[i][1] = fmaf(a, wv.y, acc[i][1]);
      acc[i][2] = fmaf(a, wv.z, acc[i][2]);
      acc[i][3] = fmaf(a, wv.w, acc[i][3]);
    }
  }
  float4 b4 = *(const float4*)&bias[tc*4];
  float s0=0,s1=0,s2=0,s3=0,q0=0,q1=0,q2=0,q3=0;
  #pragma unroll
  for (int i=0;i<8;++i) {
    int r = r0 + tr*8 + i;
    if (r < N_NODES) {
      float o0=acc[i][0]+b4.x, o1=acc[i][1]+b4.y, o2=acc[i][2]+b4.z, o3=acc[i][3]+b4.w;
      float4 ov; ov.x=o0; ov.y=o1; ov.z=o2; ov.w=o3;
      ((float4*)Out)[(size_t)r*32 + tc] = ov;
      s0+=o0;s1+=o1;s2+=o2;s3+=o3;
      q0+=o0*o0;q1+=o1*o1;q2+=o2*o2;q3+=o3*o3;
    }
  }
  __syncthreads();                 // done reading As; reuse as reduction scratch
  float* red_s = As;
  float* red_q = As + 8*DIM;
  red_s[tr*DIM + tc*4+0]=s0; red_s[tr*DIM + tc*4+1]=s1; red_s[tr*DIM + tc*4+2]=s2; red_s[tr*DIM + tc*4+3]=s3;
  red_q[tr*DIM + tc*4+0]=q0; red_q[tr*DIM + tc*4+1]=q1; red_q[tr*DIM + tc*4+2]=q2; red_q[tr*DIM + tc*4+3]=q3;
  __syncthreads();
  if (tid < DIM) {
    float ss=0.f, qq=0.f;
    #pragma unroll
    for (int t=0;t<8;++t){ ss += red_s[t*DIM+tid]; qq += red_q[t*DIM+tid]; }
    atomicAdd(&statsOut[tid],     (double)ss);
    atomicAdd(&statsOut[DIM+tid], (double)qq);
  }
}

// ---------------- BN apply (+relu), write h_next, accumulate node_rep ----------------
__global__ __launch_bounds__(256) void k_apply(
  const float* __restrict__ t2, const double* __restrict__ stats,
  const float* __restrict__ g, const float* __restrict__ b,
  float* __restrict__ hout, float* __restrict__ node_rep, int do_relu)
{
  __shared__ float s_scale[DIM], s_shift[DIM];
  int tid = threadIdx.x;
  if (tid < DIM) {
    double m = stats[tid]*(1.0/N_NODES);
    double v = stats[DIM+tid]*(1.0/N_NODES) - m*m;
    float inv = (float)(1.0/sqrt(v + (double)BNEPS));
    float sc = g[tid]*inv;
    s_scale[tid]=sc; s_shift[tid]=b[tid]-(float)m*sc;
  }
  __syncthreads();
  int total = N_NODES*32;
  int stride = gridDim.x*blockDim.x;
  for (int i = blockIdx.x*blockDim.x+tid; i<total; i+=stride) {
    int c = (i & 31)*4;
    float4 v = ((const float4*)t2)[i];
    v.x = fmaf(v.x, s_scale[c+0], s_shift[c+0]);
    v.y = fmaf(v.y, s_scale[c+1], s_shift[c+1]);
    v.z = fmaf(v.z, s_scale[c+2], s_shift[c+2]);
    v.w = fmaf(v.w, s_scale[c+3], s_shift[c+3]);
    if (do_relu){ v.x=fmaxf(v.x,0.f); v.y=fmaxf(v.y,0.f); v.z=fmaxf(v.z,0.f); v.w=fmaxf(v.w,0.f); }
    ((float4*)hout)[i] = v;
    float4 nr = ((float4*)node_rep)[i];
    nr.x+=v.x; nr.y+=v.y; nr.z+=v.z; nr.w+=v.w;
    ((float4*)node_rep)[i] = nr;
  }
}

extern "C" void kernel_launch(void* const* d_in, const int* in_sizes, int n_in,
                              void* d_out, int out_size, void* d_ws, size_t ws_size,
                              hipStream_t stream)
{
  const int*   x_feat   = (const int*)d_in[0];
  const int*   eidx     = (const int*)d_in[1];
  const int*   eattr    = (const int*)d_in[2];
  const float* nev      = (const float*)d_in[3];
  const float* nsl      = (const float*)d_in[4];
  const float* atom_emb = (const float*)d_in[5];
  const float* cw1 = (const float*)d_in[6];
  const float* cb1 = (const float*)d_in[7];
  const float* cw2 = (const float*)d_in[8];
  const float* cb2 = (const float*)d_in[9];
  const float* fw1 = (const float*)d_in[10];
  const float* fb1 = (const float*)d_in[11];
  const float* fw2 = (const float*)d_in[12];
  const float* fb2 = (const float*)d_in[13];
  const float* wm1 = (const float*)d_in[14];
  const float* wb1 = (const float*)d_in[15];
  const float* wm2 = (const float*)d_in[16];
  const float* wb2 = (const float*)d_in[17];
  const float* wm3 = (const float*)d_in[18];
  const float* wb3 = (const float*)d_in[19];
  const float* bond = (const float*)d_in[20];
  const float* conv_w1 = (const float*)d_in[21];
  const float* conv_b1 = (const float*)d_in[22];
  const float* conv_bn_g = (const float*)d_in[23];
  const float* conv_bn_b = (const float*)d_in[24];
  const float* conv_w2 = (const float*)d_in[25];
  const float* conv_b2 = (const float*)d_in[26];
  const float* conv_eps = (const float*)d_in[27];
  const float* bn_g = (const float*)d_in[28];
  const float* bn_b = (const float*)d_in[29];
  float* out = (float*)d_out;

  char* ws = (char*)d_ws;
  size_t off = 0;
  auto alloc = [&](size_t bytes)->char* {
    char* p = ws + off;
    off += (bytes + 255) & ~(size_t)255;
    return p;
  };
  float* hA       = (float*)alloc((size_t)N_NODES*DIM*4);
  float* hB       = (float*)alloc((size_t)N_NODES*DIM*4);
  float* bufP     = (float*)alloc((size_t)N_NODES*DIM*4);
  float* bufQ     = (float*)alloc((size_t)N_NODES*DIM*4);
  int*   csr_src  = (int*)alloc((size_t)N_EDGES*4);
  int*   csr_attr = (int*)alloc((size_t)N_EDGES*4);
  float* csr_w0   = (float*)alloc((size_t)N_EDGES*4);
  float* csr_w1   = (float*)alloc((size_t)N_EDGES*4);
  float* weights  = (float*)alloc((size_t)N_EDGES*4);
  int*   counts   = (int*)alloc((size_t)N_NODES*4);
  int*   offs     = (int*)alloc((size_t)(N_NODES+1)*4);
  int*   cursor   = (int*)alloc((size_t)N_NODES*4);
  float* kap      = (float*)alloc((size_t)N_NODES*4);
  float* fv       = (float*)alloc((size_t)N_NODES*4);
  float* gamma    = (float*)alloc((size_t)N_NODES*4);
  float* delta_f  = (float*)alloc((size_t)N_NODES*4);
  float* dg       = (float*)alloc((size_t)N_NODES*4);
  float* gfd      = (float*)alloc((size_t)N_NODES*4);
  int*   mask     = (int*)alloc((size_t)N_NODES*4);
  double* wh_acc  = (double*)alloc(64*8);
  float*  wh2     = (float*)alloc(64*4);
  double* kapsum  = (double*)alloc(64*8);
  double* lossacc = (double*)alloc(8);
  double* stats   = (double*)alloc((size_t)NLAYERS*512*8);

  k_init<<<64, 256, 0, stream>>>(counts, gamma, delta_f, dg, gfd, wh_acc, kapsum, lossacc);
  k_node<<<N_NODES/4, 256, 0, stream>>>(x_feat, atom_emb, cw1,cb1,cw2,cb2, fw1,fb1,fw2,fb2,
                                        hA, out, kap, fv, kapsum);
  k_edge_pre<<<256, 256, 0, stream>>>(eidx, eattr, wm1, counts, wh_acc);
  k_topk<<<1, 1024, 0, stream>>>(kap, mask);
  k_scan<<<1, 1024, 0, stream>>>(counts, offs, cursor);
  k_wmlp2<<<1, 64, 0, stream>>>(wh_acc, wb1, wm2, wb2, wh2);
  k_edge_main<<<1024, 256, 0, stream>>>(eidx, eattr, nev, wm3, wb3, wh2, fv, mask, offs, cursor,
                                        weights, gamma, delta_f, csr_src, csr_attr, csr_w0, csr_w1);
  k_edge2<<<640, 256, 0, stream>>>(eidx, weights, fv, gamma, delta_f, dg, gfd);
  k_loss<<<(N_NODES+63)/64, 256, 0, stream>>>(kap, gamma, dg, gfd, lossacc);
  k_finalize<<<1, 64, 0, stream>>>(lossacc, kapsum, out);

  float* hcur = hA; float* hnext = hB;
  for (int l=0; l<NLAYERS; ++l) {
    double* stats_l = stats + (size_t)l*512;
    const float* wsel = (l==0) ? csr_w0 : csr_w1;
    k_aggr<<<N_NODES/4, 256, 0, stream>>>(hcur, offs, csr_src, csr_attr, wsel,
                                          bond + (size_t)l*3*16*DIM, nsl, conv_eps, l,
                                          bufP, stats_l);
    k_gemm<<<(N_NODES+63)/64, 256, 0, stream>>>(bufP, conv_w1 + (size_t)l*DIM*DIM, conv_b1 + l*DIM, bufQ,
                                                (const double*)nullptr, (const float*)nullptr, (const float*)nullptr,
                                                stats_l, 0);
    k_gemm<<<(N_NODES+63)/64, 256, 0, stream>>>(bufQ, conv_w2 + (size_t)l*DIM*DIM, conv_b2 + l*DIM, bufP,
                                                stats_l, conv_bn_g + l*DIM, conv_bn_b + l*DIM,
                                                stats_l + 256, 1);
    k_apply<<<1024, 256, 0, stream>>>(bufP, stats_l+256, bn_g + l*DIM, bn_b + l*DIM,
                                      hnext, out, (l<NLAYERS-1)?1:0);
    float* t = hcur; hcur = hnext; hnext = t;
  }
}

// Round 3
// 812.373 us; speedup vs baseline: 1.1478x; 1.1478x over previous
//
#include <hip/hip_runtime.h>
#include <hip/hip_bf16.h>
#include <math.h>

#define N_NODES 10000
#define N_EDGES 320000
#define DIM     128
#define NLAYERS 5
#define CHIDN   20
#define BNEPS   1e-5f
#define TOPK    100

__device__ __forceinline__ float sigmoidf_(float x){ return 1.0f/(1.0f + expf(-x)); }

// ---------------- init: zero accumulators ----------------
__global__ void k_init(int* counts, float* gamma, float* delta_f, float* dg, float* gfd,
                       double* wh_acc, double* kapsum, double* lossacc)
{
  int i = blockIdx.x*blockDim.x + threadIdx.x;
  int stride = gridDim.x*blockDim.x;
  for (int j=i; j<N_NODES; j+=stride){ counts[j]=0; gamma[j]=0.f; delta_f[j]=0.f; dg[j]=0.f; gfd[j]=0.f; }
  if (i < 64){ wh_acc[i]=0.0; kapsum[i]=0.0; lossacc[i]=0.0; }
}

// ---------------- node embed + kappa/f MLPs ----------------
__global__ __launch_bounds__(256) void k_node(
  const int* __restrict__ xf, const float* __restrict__ atom_emb,
  const float* __restrict__ cw1, const float* __restrict__ cb1,
  const float* __restrict__ cw2, const float* __restrict__ cb2,
  const float* __restrict__ fw1, const float* __restrict__ fb1,
  const float* __restrict__ fw2, const float* __restrict__ fb2,
  float* __restrict__ x_out, float* __restrict__ kap, float* __restrict__ fv,
  double* __restrict__ kapsum)
{
  __shared__ float scw1[DIM*CHIDN];
  __shared__ float sfw1[DIM*CHIDN];
  __shared__ float sx[4][DIM];
  __shared__ float sred[4][64];
  int tid = threadIdx.x;
  for (int i=tid;i<DIM*CHIDN;i+=256){ scw1[i]=cw1[i]; sfw1[i]=fw1[i]; }
  int wid = tid>>6, lane = tid&63;
  int n = blockIdx.x*4 + wid;     // N_NODES = 4*2500 exactly
  const float* e0 = atom_emb;
  const float* e1 = atom_emb + 128*DIM;
  int f0 = xf[n*2+0], f1 = xf[n*2+1];
  float2 a = *(const float2*)(e0 + f0*DIM + lane*2);
  float2 b = *(const float2*)(e1 + f1*DIM + lane*2);
  float2 xv; xv.x = a.x+b.x; xv.y = a.y+b.y;
  *(float2*)(x_out + (size_t)n*DIM + lane*2) = xv;
  sx[wid][lane*2] = xv.x; sx[wid][lane*2+1] = xv.y;
  __syncthreads();
  if (lane < CHIDN) {
    float acc = cb1[lane];
    for (int d=0; d<DIM; ++d) acc = fmaf(sx[wid][d], scw1[d*CHIDN+lane], acc);
    sred[wid][lane] = fmaxf(acc, 0.f) * cw2[lane];
  } else if (lane >= 32 && lane < 32+CHIDN) {
    int hh = lane-32;
    float acc = fb1[hh];
    for (int d=0; d<DIM; ++d) acc = fmaf(sx[wid][d], sfw1[d*CHIDN+hh], acc);
    sred[wid][32+hh] = fmaxf(acc, 0.f) * fw2[hh];
  }
  __syncthreads();
  if (lane == 0) {
    float s = cb2[0];
    for (int h=0;h<CHIDN;++h) s += sred[wid][h];
    float kp = sigmoidf_(s);
    kap[n] = kp;
    sred[wid][62] = kp;
  } else if (lane == 1) {
    float s = fb2[0];
    for (int h=0;h<CHIDN;++h) s += sred[wid][32+h];
    fv[n] = sigmoidf_(s);
  }
  __syncthreads();
  if (tid == 0) {
    double ks = (double)sred[0][62] + (double)sred[1][62] + (double)sred[2][62] + (double)sred[3][62];
    atomicAdd(&kapsum[blockIdx.x & 63], ks);
  }
}

// ---------------- edge pre: in-degree rank + ea@wm_w1 reduction ----------------
// grid 1250 x 256: one 64-edge chunk per wave (5000 chunks total)
__global__ __launch_bounds__(256) void k_edge_pre(
  const int* __restrict__ ei, const int* __restrict__ eattr,
  const float* __restrict__ w1, int* __restrict__ counts, int* __restrict__ rank,
  double* __restrict__ wh_acc)
{
  __shared__ float part_[4][64];
  int tid = threadIdx.x;
  int wid = tid>>6, lane = tid&63;
  int bb = blockIdx.x*4 + wid;     // chunk id 0..4999
  int e = bb*64 + lane;
  int a0=eattr[e*3], a1=eattr[e*3+1], a2=eattr[e*3+2];
  float ea = (float)(a0+a1+a2);
  int dst = ei[N_EDGES+e];
  rank[e] = atomicAdd(&counts[dst], 1);
  const float* wrow = w1 + (size_t)bb*64*64;
  float acc = 0.f;
  #pragma unroll 16
  for (int t=0;t<64;++t) {
    float eat = __shfl(ea, t);
    acc = fmaf(eat, wrow[t*64 + lane], acc);
  }
  part_[wid][lane] = acc;
  __syncthreads();
  if (tid < 64) {
    float s = part_[0][tid]+part_[1][tid]+part_[2][tid]+part_[3][tid];
    atomicAdd(&wh_acc[tid], (double)s);
  }
}

// ---------------- block 0: exact top-100 radix select; block 1: scan counts ----------------
__global__ __launch_bounds__(1024) void k_topk_scan(
  const float* __restrict__ kap, int* __restrict__ mask,
  const int* __restrict__ counts, int* __restrict__ offs)
{
  __shared__ int sbuf[1024];
  __shared__ int hist[256];
  __shared__ unsigned s_prefix;
  __shared__ int s_krem;
  int tid = threadIdx.x;
  if (blockIdx.x == 0) {
    unsigned prefix = 0; int krem = TOPK;
    for (int pass=3; pass>=0; --pass) {
      if (tid<256) hist[tid]=0;
      __syncthreads();
      int shift = pass*8;
      unsigned hi_mask = (pass==3) ? 0u : (0xFFFFFFFFu << (shift+8));
      for (int i=tid;i<N_NODES;i+=1024) {
        unsigned b = __float_as_uint(kap[i]);
        if ((b & hi_mask) == (prefix & hi_mask))
          atomicAdd(&hist[(b>>shift)&255], 1);
      }
      __syncthreads();
      if (tid==0) {
        int c=0; int b=255;
        for (; b>0; --b){ int h=hist[b]; if (c+h >= krem) break; c+=h; }
        s_prefix = prefix | ((unsigned)b << shift);
        s_krem = krem - c;
      }
      __syncthreads();
      prefix = s_prefix; krem = s_krem;
      __syncthreads();
    }
    unsigned thr = prefix;
    const int per = 10;
    int base = tid*per;
    int cnt = 0;
    for (int i=base; i<base+per && i<N_NODES; ++i)
      if (__float_as_uint(kap[i])==thr) cnt++;
    sbuf[tid]=cnt; __syncthreads();
    for (int off=1; off<1024; off<<=1){
      int t = (tid>=off)? sbuf[tid-off] : 0;
      __syncthreads();
      sbuf[tid] += t;
      __syncthreads();
    }
    int taken = sbuf[tid] - cnt;
    for (int i=base; i<base+per && i<N_NODES; ++i) {
      unsigned b = __float_as_uint(kap[i]);
      int sel;
      if (b > thr) sel = 1;
      else if (b == thr) { sel = (taken < krem) ? 1 : 0; taken++; }
      else sel = 0;
      mask[i] = sel;
    }
  } else {
    int run = 0;
    for (int chunk=0; chunk<10; ++chunk) {
      int i = chunk*1024 + tid;
      int v = (i<N_NODES)? counts[i] : 0;
      sbuf[tid]=v; __syncthreads();
      for (int off=1; off<1024; off<<=1){
        int t = (tid>=off)? sbuf[tid-off]:0;
        __syncthreads();
        sbuf[tid]+=t;
        __syncthreads();
      }
      if (i<N_NODES) offs[i+1] = run + sbuf[tid];
      run += sbuf[1023];
      __syncthreads();
    }
    if (tid==0) offs[0]=0;
  }
}

// ---------------- streaming: wh2 (folded MLP layer 2) + per-edge weights ----------------
// grid 1250 x 256, one edge per thread
__global__ __launch_bounds__(256) void k_weights(
  const double* __restrict__ wh_acc, const float* __restrict__ wb1,
  const float* __restrict__ wm2, const float* __restrict__ wb2,
  const float* __restrict__ w3, const float* __restrict__ wb3,
  float* __restrict__ weights)
{
  __shared__ float h1[64], h2[64];
  int tid = threadIdx.x;
  if (tid < 64) h1[tid] = fmaxf((float)wh_acc[tid] + wb1[tid], 0.f);
  __syncthreads();
  if (tid < 64) {
    float a = wb2[tid];
    for (int k=0;k<64;++k) a = fmaf(h1[k], wm2[k*64+tid], a);
    h2[tid] = fmaxf(a, 0.f);
  }
  __syncthreads();
  int e = blockIdx.x*256 + tid;
  float ws = wb3[e];
  #pragma unroll 16
  for (int h=0; h<64; ++h) ws = fmaf(h2[h], w3[(size_t)h*N_EDGES + e], ws);
  weights[e] = sigmoidf_(ws);
}

// ---------------- CSR fill (packed int4, no cursor atomic) + gamma/delta_f ----------------
__global__ __launch_bounds__(256) void k_csr_fill(
  const int* __restrict__ ei, const int* __restrict__ eattr,
  const float* __restrict__ nev, const float* __restrict__ weights,
  const float* __restrict__ fv, const int* __restrict__ mask,
  const int* __restrict__ offs, const int* __restrict__ rank,
  float* __restrict__ gamma, float* __restrict__ delta_f,
  int4* __restrict__ csr)
{
  int e = blockIdx.x*256 + threadIdx.x;
  int s = ei[e], d = ei[N_EDGES + e];
  float wt = weights[e];
  float fd = fv[d] - fv[s];
  atomicAdd(&gamma[s], 0.5f*wt*fd*fd);
  atomicAdd(&delta_f[s], wt*fd);
  int a0 = eattr[e*3], a1 = eattr[e*3+1], a2 = eattr[e*3+2];
  float ew = nev[e];
  float mew = (mask[s] | mask[d]) ? 1e-5f : 1.0f;
  int4 rec;
  rec.x = s;
  rec.y = a0 | (a1<<8) | (a2<<16);
  rec.z = __float_as_int(ew);
  rec.w = __float_as_int(mew*ew);
  csr[offs[d] + rank[e]] = rec;
}

// ---------------- second curvature pass ----------------
__global__ __launch_bounds__(256) void k_edge2(
  const int* __restrict__ ei, const float* __restrict__ weights,
  const float* __restrict__ fv, const float* __restrict__ gamma,
  const float* __restrict__ delta_f,
  float* __restrict__ dg, float* __restrict__ gfd)
{
  int e = blockIdx.x*256 + threadIdx.x;
  int s = ei[e], d = ei[N_EDGES+e];
  float wt = weights[e];
  atomicAdd(&dg[s], wt*(gamma[d]-gamma[s]));
  float fd = fv[d]-fv[s];
  atomicAdd(&gfd[s], wt*fd*(delta_f[d]-delta_f[s]));
}

// ---------------- N x N curvature loss: grid (157 j-tiles, 8 i-tiles) ----------------
__global__ __launch_bounds__(256) void k_loss(
  const float* __restrict__ kap, const float* __restrict__ gamma,
  const float* __restrict__ dg, const float* __restrict__ gfd,
  double* __restrict__ lossacc)
{
  __shared__ float skap[1250];
  __shared__ double dred[256];
  int tid = threadIdx.x;
  int i0 = blockIdx.y*1250;
  for (int i=tid;i<1250;i+=256) skap[i]=kap[i0+i];
  __syncthreads();
  int lane = tid & 63, part = tid >> 6;
  int j = blockIdx.x*64 + lane;
  float g=0.f, g2=0.f;
  bool valid = j < N_NODES;
  if (valid){ g = gamma[j]; g2 = 0.5f*(dg[j]-gfd[j]); }
  float sum = 0.f;
  if (valid) {
    int a = part*313, b = a+313; if (b>1250) b=1250;
    for (int i=a;i<b;++i) sum += fmaxf(fmaf(skap[i], g, -g2), 0.f);
  }
  dred[tid] = (double)sum;
  __syncthreads();
  for (int off=128; off>0; off>>=1){
    if (tid<off) dred[tid]+=dred[tid+off];
    __syncthreads();
  }
  if (tid==0) atomicAdd(&lossacc[blockIdx.x & 63], dred[0]);
}

__global__ void k_finalize(const double* __restrict__ lossacc, const double* __restrict__ kapsum,
                           float* __restrict__ out)
{
  if (threadIdx.x==0 && blockIdx.x==0){
    double acc = 0;
    for (int i=0;i<64;++i) acc += lossacc[i] - kapsum[i];
    out[N_NODES*DIM] = (float)acc;
  }
}

// ---------------- aggregation with fused input BN+relu ----------------
__global__ __launch_bounds__(256) void k_aggr(
  const float* __restrict__ hsrc, const double* __restrict__ statsPrev,
  const float* __restrict__ gPrev, const float* __restrict__ bPrev,
  const int4* __restrict__ csr, const int* __restrict__ offs,
  const float* __restrict__ bond_l, const float* __restrict__ nsl,
  const float* __restrict__ conv_eps, int l, int useW1,
  float* __restrict__ outP, double* __restrict__ stats_l)
{
  __shared__ float tab[3*16*DIM];       // 24 KB
  __shared__ float s_sc[DIM], s_sh[DIM];
  int tid = threadIdx.x;
  for (int i=tid; i<3*16*DIM; i+=256) tab[i] = bond_l[i];
  bool bn = (statsPrev != nullptr);
  if (bn && tid < DIM) {
    double m = statsPrev[tid] * (1.0/N_NODES);
    double v = statsPrev[DIM+tid] * (1.0/N_NODES) - m*m;
    float inv = (float)(1.0/sqrt(v + (double)BNEPS));
    float sc = gPrev[tid]*inv;
    s_sc[tid]=sc; s_sh[tid]=bPrev[tid]-(float)m*sc;
  }
  if (blockIdx.x == 0) {
    for (int i=tid; i<512; i+=256) stats_l[i] = 0.0;
  }
  __syncthreads();
  int wid = tid>>6, lane = tid&63;
  int n = blockIdx.x*4 + wid;
  float scx=1.f, scy=1.f, shx=0.f, shy=0.f;
  if (bn){ scx=s_sc[lane*2]; scy=s_sc[lane*2+1]; shx=s_sh[lane*2]; shy=s_sh[lane*2+1]; }
  float2 h0 = *(const float2*)(hsrc + (size_t)n*DIM + lane*2);
  if (bn){ h0.x = fmaxf(fmaf(h0.x,scx,shx),0.f); h0.y = fmaxf(fmaf(h0.y,scy,shy),0.f); }
  float c = conv_eps[l] * nsl[n];
  float ax = c*h0.x, ay = c*h0.y;
  int beg = offs[n], end = offs[n+1];
  for (int j0=beg; j0<end; j0+=64) {
    int m = end - j0; if (m>64) m=64;
    int4 rec; rec.x=0; rec.y=0; rec.z=0; rec.w=0;
    float wsel = 0.f;
    if (lane < m) { rec = csr[j0+lane]; wsel = __int_as_float(useW1 ? rec.w : rec.z); }
    for (int t=0;t<m;++t) {
      int st = __shfl(rec.x, t);
      int a  = __shfl(rec.y, t);
      float wt = __shfl(wsel, t);
      float2 hs = *(const float2*)(hsrc + (size_t)st*DIM + lane*2);
      if (bn){ hs.x = fmaxf(fmaf(hs.x,scx,shx),0.f); hs.y = fmaxf(fmaf(hs.y,scy,shy),0.f); }
      int a0 = a&255, a1=(a>>8)&255, a2=(a>>16)&255;
      float2 e0 = *(const float2*)(tab + a0*DIM + lane*2);
      float2 e1 = *(const float2*)(tab + 16*DIM + a1*DIM + lane*2);
      float2 e2 = *(const float2*)(tab + 32*DIM + a2*DIM + lane*2);
      float vx = hs.x + e0.x + e1.x + e2.x;
      float vy = hs.y + e0.y + e1.y + e2.y;
      ax = fmaf(wt, fmaxf(vx,0.f), ax);
      ay = fmaf(wt, fmaxf(vy,0.f), ay);
    }
  }
  float2 o; o.x=ax; o.y=ay;
  *(float2*)(outP + (size_t)n*DIM + lane*2) = o;
}

// ---------------- 64x64-tile GEMM, optional fused BN+relu on input, stats epilogue ----------------
// grid: dim3(157, 2), block 256. LDS ~68 KB -> 2 blocks/CU.
__global__ __launch_bounds__(256) void k_gemm(
  const float* __restrict__ A, const float* __restrict__ W,
  const float* __restrict__ bias, float* __restrict__ Out,
  const double* __restrict__ statsIn, const float* __restrict__ gin, const float* __restrict__ bin,
  double* __restrict__ statsOut, int useBnIn)
{
  __shared__ __align__(16) float As[DIM*68];   // As[k*68 + r], transposed, padded
  __shared__ __align__(16) float Ws[DIM*64];   // Ws[k*64 + c]
  __shared__ float s_scale[DIM], s_shift[DIM];
  int tid = threadIdx.x;
  int r0 = blockIdx.x*64, c0 = blockIdx.y*64;
  if (useBnIn) {
    if (tid < DIM) {
      double m = statsIn[tid] * (1.0/N_NODES);
      double v = statsIn[DIM+tid] * (1.0/N_NODES) - m*m;
      float inv = (float)(1.0 / sqrt(v + (double)BNEPS));
      float sc = gin[tid]*inv;
      s_scale[tid] = sc;
      s_shift[tid] = bin[tid] - (float)m*sc;
    }
    __syncthreads();
  }
  // stage W half: 128 x 64
  for (int i=tid; i<2048; i+=256) {
    int k = i>>4, c4 = i&15;
    *(float4*)(&Ws[k*64 + c4*4]) = *(const float4*)(W + k*DIM + c0 + c4*4);
  }
  // stage A transposed (strided global read, L2-resident; conflict-free LDS writes)
  for (int i=tid; i<2048; i+=256) {
    int r = i&63, k4 = i>>6;
    int row = r0 + r;
    float4 v;
    if (row < N_NODES) v = *(const float4*)(A + (size_t)row*DIM + k4*4);
    else { v.x=0.f;v.y=0.f;v.z=0.f;v.w=0.f; }
    if (useBnIn) {
      int k = k4*4;
      v.x = fmaxf(fmaf(v.x, s_scale[k+0], s_shift[k+0]), 0.f);
      v.y = fmaxf(fmaf(v.y, s_scale[k+1], s_shift[k+1]), 0.f);
      v.z = fmaxf(fmaf(v.z, s_scale[k+2], s_shift[k+2]), 0.f);
      v.w = fmaxf(fmaf(v.w, s_scale[k+3], s_shift[k+3]), 0.f);
    }
    As[(k4*4+0)*68 + r] = v.x;
    As[(k4*4+1)*68 + r] = v.y;
    As[(k4*4+2)*68 + r] = v.z;
    As[(k4*4+3)*68 + r] = v.w;
  }
  __syncthreads();
  int tc = tid & 15, tr = tid >> 4;
  float acc[4][4];
  #pragma unroll
  for (int i=0;i<4;++i){ acc[i][0]=0.f; acc[i][1]=0.f; acc[i][2]=0.f; acc[i][3]=0.f; }
  #pragma unroll 4
  for (int k=0;k<DIM;++k) {
    float4 a4 = *(const float4*)(&As[k*68 + tr*4]);
    float4 w4 = *(const float4*)(&Ws[k*64 + tc*4]);
    acc[0][0]=fmaf(a4.x,w4.x,acc[0][0]); acc[0][1]=fmaf(a4.x,w4.y,acc[0][1]);
    acc[0][2]=fmaf(a4.x,w4.z,acc[0][2]); acc[0][3]=fmaf(a4.x,w4.w,acc[0][3]);
    acc[1][0]=fmaf(a4.y,w4.x,acc[1][0]); acc[1][1]=fmaf(a4.y,w4.y,acc[1][1]);
    acc[1][2]=fmaf(a4.y,w4.z,acc[1][2]); acc[1][3]=fmaf(a4.y,w4.w,acc[1][3]);
    acc[2][0]=fmaf(a4.z,w4.x,acc[2][0]); acc[2][1]=fmaf(a4.z,w4.y,acc[2][1]);
    acc[2][2]=fmaf(a4.z,w4.z,acc[2][2]); acc[2][3]=fmaf(a4.z,w4.w,acc[2][3]);
    acc[3][0]=fmaf(a4.w,w4.x,acc[3][0]); acc[3][1]=fmaf(a4.w,w4.y,acc[3][1]);
    acc[3][2]=fmaf(a4.w,w4.z,acc[3][2]); acc[3][3]=fmaf(a4.w,w4.w,acc[3][3]);
  }
  __syncthreads();   // done with Ws/As reads; reuse Ws as stat scratch
  float4 b4 = *(const float4*)(bias + c0 + tc*4);
  float ss[4]={0.f,0.f,0.f,0.f}, qq[4]={0.f,0.f,0.f,0.f};
  #pragma unroll
  for (int i=0;i<4;++i) {
    int row = r0 + tr*4 + i;
    if (row < N_NODES) {
      float o0=acc[i][0]+b4.x, o1=acc[i][1]+b4.y, o2=acc[i][2]+b4.z, o3=acc[i][3]+b4.w;
      float4 ov; ov.x=o0; ov.y=o1; ov.z=o2; ov.w=o3;
      *(float4*)(Out + (size_t)row*DIM + c0 + tc*4) = ov;
      ss[0]+=o0; ss[1]+=o1; ss[2]+=o2; ss[3]+=o3;
      qq[0]+=o0*o0; qq[1]+=o1*o1; qq[2]+=o2*o2; qq[3]+=o3*o3;
    }
  }
  float* rs = Ws;
  float* rq = Ws + 1024;
  #pragma unroll
  for (int j=0;j<4;++j){ rs[tr*64 + tc*4+j]=ss[j]; rq[tr*64 + tc*4+j]=qq[j]; }
  __syncthreads();
  if (tid < 64) {
    float s=0.f, q=0.f;
    #pragma unroll
    for (int t=0;t<16;++t){ s += rs[t*64+tid]; q += rq[t*64+tid]; }
    atomicAdd(&statsOut[c0+tid],       (double)s);
    atomicAdd(&statsOut[DIM+c0+tid],   (double)q);
  }
}

// ---------------- final: node_rep = x + sum_l act(BN_l(t2_l)) ----------------
__global__ __launch_bounds__(256) void k_final(
  const float* __restrict__ x,
  const float* __restrict__ t0, const float* __restrict__ t1, const float* __restrict__ t2,
  const float* __restrict__ t3, const float* __restrict__ t4,
  const double* __restrict__ stats, const float* __restrict__ bn_g, const float* __restrict__ bn_b,
  float* __restrict__ out)
{
  __shared__ float sc[5][DIM], sh[5][DIM];
  int tid = threadIdx.x;
  if (tid < DIM) {
    for (int l=0;l<5;++l) {
      const double* st = stats + (size_t)l*512 + 256;
      double m = st[tid]*(1.0/N_NODES);
      double v = st[DIM+tid]*(1.0/N_NODES) - m*m;
      float inv = (float)(1.0/sqrt(v + (double)BNEPS));
      float s = bn_g[l*DIM+tid]*inv;
      sc[l][tid]=s; sh[l][tid]=bn_b[l*DIM+tid]-(float)m*s;
    }
  }
  __syncthreads();
  const float* ts[5] = {t0,t1,t2,t3,t4};
  int total = N_NODES*32;
  int stride = gridDim.x*256;
  for (int i = blockIdx.x*256 + tid; i < total; i += stride) {
    int c = (i & 31)*4;
    float4 a = ((const float4*)x)[i];
    #pragma unroll
    for (int l=0;l<5;++l) {
      float4 v = ((const float4*)ts[l])[i];
      v.x = fmaf(v.x, sc[l][c+0], sh[l][c+0]);
      v.y = fmaf(v.y, sc[l][c+1], sh[l][c+1]);
      v.z = fmaf(v.z, sc[l][c+2], sh[l][c+2]);
      v.w = fmaf(v.w, sc[l][c+3], sh[l][c+3]);
      if (l < 4) { v.x=fmaxf(v.x,0.f); v.y=fmaxf(v.y,0.f); v.z=fmaxf(v.z,0.f); v.w=fmaxf(v.w,0.f); }
      a.x+=v.x; a.y+=v.y; a.z+=v.z; a.w+=v.w;
    }
    ((float4*)out)[i] = a;
  }
}

extern "C" void kernel_launch(void* const* d_in, const int* in_sizes, int n_in,
                              void* d_out, int out_size, void* d_ws, size_t ws_size,
                              hipStream_t stream)
{
  const int*   x_feat   = (const int*)d_in[0];
  const int*   eidx     = (const int*)d_in[1];
  const int*   eattr    = (const int*)d_in[2];
  const float* nev      = (const float*)d_in[3];
  const float* nsl      = (const float*)d_in[4];
  const float* atom_emb = (const float*)d_in[5];
  const float* cw1 = (const float*)d_in[6];
  const float* cb1 = (const float*)d_in[7];
  const float* cw2 = (const float*)d_in[8];
  const float* cb2 = (const float*)d_in[9];
  const float* fw1 = (const float*)d_in[10];
  const float* fb1 = (const float*)d_in[11];
  const float* fw2 = (const float*)d_in[12];
  const float* fb2 = (const float*)d_in[13];
  const float* wm1 = (const float*)d_in[14];
  const float* wb1 = (const float*)d_in[15];
  const float* wm2 = (const float*)d_in[16];
  const float* wb2 = (const float*)d_in[17];
  const float* wm3 = (const float*)d_in[18];
  const float* wb3 = (const float*)d_in[19];
  const float* bond = (const float*)d_in[20];
  const float* conv_w1 = (const float*)d_in[21];
  const float* conv_b1 = (const float*)d_in[22];
  const float* conv_bn_g = (const float*)d_in[23];
  const float* conv_bn_b = (const float*)d_in[24];
  const float* conv_w2 = (const float*)d_in[25];
  const float* conv_b2 = (const float*)d_in[26];
  const float* conv_eps = (const float*)d_in[27];
  const float* bn_g = (const float*)d_in[28];
  const float* bn_b = (const float*)d_in[29];
  float* out = (float*)d_out;

  char* ws = (char*)d_ws;
  size_t off = 0;
  auto alloc = [&](size_t bytes)->char* {
    char* p = ws + off;
    off += (bytes + 255) & ~(size_t)255;
    return p;
  };
  float* hA       = (float*)alloc((size_t)N_NODES*DIM*4);
  float* bufP     = (float*)alloc((size_t)N_NODES*DIM*4);
  float* bufQ     = (float*)alloc((size_t)N_NODES*DIM*4);
  float* t2b[NLAYERS];
  for (int l=0;l<NLAYERS;++l) t2b[l] = (float*)alloc((size_t)N_NODES*DIM*4);
  int4*  csr      = (int4*)alloc((size_t)N_EDGES*16);
  float* weights  = (float*)alloc((size_t)N_EDGES*4);
  int*   rank     = (int*)alloc((size_t)N_EDGES*4);
  int*   counts   = (int*)alloc((size_t)N_NODES*4);
  int*   offs     = (int*)alloc((size_t)(N_NODES+1)*4);
  float* kap      = (float*)alloc((size_t)N_NODES*4);
  float* fv       = (float*)alloc((size_t)N_NODES*4);
  float* gamma    = (float*)alloc((size_t)N_NODES*4);
  float* delta_f  = (float*)alloc((size_t)N_NODES*4);
  float* dg       = (float*)alloc((size_t)N_NODES*4);
  float* gfd      = (float*)alloc((size_t)N_NODES*4);
  int*   mask     = (int*)alloc((size_t)N_NODES*4);
  double* wh_acc  = (double*)alloc(64*8);
  double* kapsum  = (double*)alloc(64*8);
  double* lossacc = (double*)alloc(64*8);
  double* stats   = (double*)alloc((size_t)NLAYERS*512*8);

  k_init<<<64, 256, 0, stream>>>(counts, gamma, delta_f, dg, gfd, wh_acc, kapsum, lossacc);
  k_node<<<N_NODES/4, 256, 0, stream>>>(x_feat, atom_emb, cw1,cb1,cw2,cb2, fw1,fb1,fw2,fb2,
                                        hA, kap, fv, kapsum);
  k_edge_pre<<<N_EDGES/256, 256, 0, stream>>>(eidx, eattr, wm1, counts, rank, wh_acc);
  k_topk_scan<<<2, 1024, 0, stream>>>(kap, mask, counts, offs);
  k_weights<<<N_EDGES/256, 256, 0, stream>>>(wh_acc, wb1, wm2, wb2, wm3, wb3, weights);
  k_csr_fill<<<N_EDGES/256, 256, 0, stream>>>(eidx, eattr, nev, weights, fv, mask, offs, rank,
                                              gamma, delta_f, csr);
  k_edge2<<<N_EDGES/256, 256, 0, stream>>>(eidx, weights, fv, gamma, delta_f, dg, gfd);
  k_loss<<<dim3((N_NODES+63)/64, 8), 256, 0, stream>>>(kap, gamma, dg, gfd, lossacc);
  k_finalize<<<1, 64, 0, stream>>>(lossacc, kapsum, out);

  for (int l=0; l<NLAYERS; ++l) {
    double* stats_l = stats + (size_t)l*512;
    const float* hsrc = (l==0) ? hA : t2b[l-1];
    const double* statsPrev = (l==0) ? nullptr : (stats + (size_t)(l-1)*512 + 256);
    const float* gPrev = bn_g + (size_t)(l>0?l-1:0)*DIM;
    const float* bPrev = bn_b + (size_t)(l>0?l-1:0)*DIM;
    k_aggr<<<N_NODES/4, 256, 0, stream>>>(hsrc, statsPrev, gPrev, bPrev, csr, offs,
                                          bond + (size_t)l*3*16*DIM, nsl, conv_eps, l,
                                          (l>0)?1:0, bufP, stats_l);
    k_gemm<<<dim3((N_NODES+63)/64, 2), 256, 0, stream>>>(bufP, conv_w1 + (size_t)l*DIM*DIM,
                conv_b1 + l*DIM, bufQ,
                (const double*)nullptr, (const float*)nullptr, (const float*)nullptr,
                stats_l, 0);
    k_gemm<<<dim3((N_NODES+63)/64, 2), 256, 0, stream>>>(bufQ, conv_w2 + (size_t)l*DIM*DIM,
                conv_b2 + l*DIM, t2b[l],
                stats_l, conv_bn_g + l*DIM, conv_bn_b + l*DIM,
                stats_l + 256, 1);
  }
  k_final<<<1024, 256, 0, stream>>>(hA, t2b[0], t2b[1], t2b[2], t2b[3], t2b[4],
                                    stats, bn_g, bn_b, out);
}

// Round 5
// 724.285 us; speedup vs baseline: 1.2874x; 1.1216x over previous
//
#include <hip/hip_runtime.h>
#include <hip/hip_bf16.h>
#include <math.h>

#define N_NODES 10000
#define N_EDGES 320000
#define DIM     128
#define NLAYERS 5
#define CHIDN   20
#define BNEPS   1e-5f
#define TOPK    100

__device__ __forceinline__ float sigmoidf_(float x){ return 1.0f/(1.0f + expf(-x)); }

// ---------------- node embed + kappa/f MLPs + zero accumulators ----------------
__global__ __launch_bounds__(256) void k_node(
  const int* __restrict__ xf, const float* __restrict__ atom_emb,
  const float* __restrict__ cw1, const float* __restrict__ cb1,
  const float* __restrict__ cw2, const float* __restrict__ cb2,
  const float* __restrict__ fw1, const float* __restrict__ fb1,
  const float* __restrict__ fw2, const float* __restrict__ fb2,
  float* __restrict__ x_out, float* __restrict__ kap, float* __restrict__ fv,
  float* __restrict__ kapparts,
  int* __restrict__ counts, float* __restrict__ gamma, float* __restrict__ delta_f,
  float* __restrict__ dg, float* __restrict__ gfd, double* __restrict__ wh_acc)
{
  __shared__ float scw1[DIM*CHIDN];
  __shared__ float sfw1[DIM*CHIDN];
  __shared__ float sx[4][DIM];
  __shared__ float sred[4][64];
  int tid = threadIdx.x;
  // zeroing (serial-stream safety: all consumers launch after this kernel)
  if (tid < 4) {
    int n = blockIdx.x*4 + tid;
    counts[n]=0; gamma[n]=0.f; delta_f[n]=0.f; dg[n]=0.f; gfd[n]=0.f;
  }
  if (blockIdx.x == 0 && tid < 64) wh_acc[tid] = 0.0;
  for (int i=tid;i<DIM*CHIDN;i+=256){ scw1[i]=cw1[i]; sfw1[i]=fw1[i]; }
  int wid = tid>>6, lane = tid&63;
  int n = blockIdx.x*4 + wid;     // N_NODES = 4*2500 exactly
  const float* e0 = atom_emb;
  const float* e1 = atom_emb + 128*DIM;
  int f0 = xf[n*2+0], f1 = xf[n*2+1];
  float2 a = *(const float2*)(e0 + f0*DIM + lane*2);
  float2 b = *(const float2*)(e1 + f1*DIM + lane*2);
  float2 xv; xv.x = a.x+b.x; xv.y = a.y+b.y;
  *(float2*)(x_out + (size_t)n*DIM + lane*2) = xv;
  sx[wid][lane*2] = xv.x; sx[wid][lane*2+1] = xv.y;
  __syncthreads();
  if (lane < CHIDN) {
    float acc = cb1[lane];
    for (int d=0; d<DIM; ++d) acc = fmaf(sx[wid][d], scw1[d*CHIDN+lane], acc);
    sred[wid][lane] = fmaxf(acc, 0.f) * cw2[lane];
  } else if (lane >= 32 && lane < 32+CHIDN) {
    int hh = lane-32;
    float acc = fb1[hh];
    for (int d=0; d<DIM; ++d) acc = fmaf(sx[wid][d], sfw1[d*CHIDN+hh], acc);
    sred[wid][32+hh] = fmaxf(acc, 0.f) * fw2[hh];
  }
  __syncthreads();
  if (lane == 0) {
    float s = cb2[0];
    for (int h=0;h<CHIDN;++h) s += sred[wid][h];
    float kp = sigmoidf_(s);
    kap[n] = kp;
    sred[wid][62] = kp;
  } else if (lane == 1) {
    float s = fb2[0];
    for (int h=0;h<CHIDN;++h) s += sred[wid][32+h];
    fv[n] = sigmoidf_(s);
  }
  __syncthreads();
  if (tid == 0) {
    kapparts[blockIdx.x] = sred[0][62] + sred[1][62] + sred[2][62] + sred[3][62];
  }
}

// ---------------- edge pre: in-degree rank + ea@wm_w1 reduction (float4 rows) ----------------
// grid 1250 x 256: one 64-edge chunk per wave (5000 chunks)
__global__ __launch_bounds__(256) void k_edge_pre(
  const int* __restrict__ ei, const int* __restrict__ eattr,
  const float* __restrict__ w1, int* __restrict__ counts, int* __restrict__ rank,
  double* __restrict__ wh_acc)
{
  __shared__ float part_[4][64];
  int tid = threadIdx.x;
  int wid = tid>>6, lane = tid&63;
  int bb = blockIdx.x*4 + wid;     // chunk id 0..4999
  int e = bb*64 + lane;
  int a0=eattr[e*3], a1=eattr[e*3+1], a2=eattr[e*3+2];
  float ea = (float)(a0+a1+a2);
  int dst = ei[N_EDGES+e];
  rank[e] = atomicAdd(&counts[dst], 1);
  // lane l covers rows (i*4 + (l>>4)) of the chunk, cols (l&15)*4..+3
  const float4* wrow = (const float4*)(w1 + (size_t)bb*64*64);
  int rsub = lane>>4, c4 = lane&15;
  float4 acc; acc.x=0.f; acc.y=0.f; acc.z=0.f; acc.w=0.f;
  #pragma unroll
  for (int i=0;i<16;++i) {
    float4 v = wrow[(i*4+rsub)*16 + c4];
    float eat = __shfl(ea, i*4+rsub);
    acc.x = fmaf(eat, v.x, acc.x);
    acc.y = fmaf(eat, v.y, acc.y);
    acc.z = fmaf(eat, v.z, acc.z);
    acc.w = fmaf(eat, v.w, acc.w);
  }
  // reduce across the 4 row-subgroups (lanes differing in bits 4,5)
  acc.x += __shfl_xor(acc.x, 16); acc.y += __shfl_xor(acc.y, 16);
  acc.z += __shfl_xor(acc.z, 16); acc.w += __shfl_xor(acc.w, 16);
  acc.x += __shfl_xor(acc.x, 32); acc.y += __shfl_xor(acc.y, 32);
  acc.z += __shfl_xor(acc.z, 32); acc.w += __shfl_xor(acc.w, 32);
  if (lane < 16) ((float4*)part_[wid])[c4] = acc;
  __syncthreads();
  if (tid < 64) {
    float s = part_[0][tid]+part_[1][tid]+part_[2][tid]+part_[3][tid];
    atomicAdd(&wh_acc[tid], (double)s);
  }
}

// ---------------- block 0: exact top-100 radix select; block 1: scan counts ----------------
__global__ __launch_bounds__(1024) void k_topk_scan(
  const float* __restrict__ kap, int* __restrict__ mask,
  const int* __restrict__ counts, int* __restrict__ offs)
{
  __shared__ int sbuf[1024];
  __shared__ int hist[256];
  __shared__ unsigned s_prefix;
  __shared__ int s_krem;
  int tid = threadIdx.x;
  if (blockIdx.x == 0) {
    unsigned prefix = 0; int krem = TOPK;
    for (int pass=3; pass>=0; --pass) {
      if (tid<256) hist[tid]=0;
      __syncthreads();
      int shift = pass*8;
      unsigned hi_mask = (pass==3) ? 0u : (0xFFFFFFFFu << (shift+8));
      for (int i=tid;i<N_NODES;i+=1024) {
        unsigned b = __float_as_uint(kap[i]);
        if ((b & hi_mask) == (prefix & hi_mask))
          atomicAdd(&hist[(b>>shift)&255], 1);
      }
      __syncthreads();
      if (tid==0) {
        int c=0; int b=255;
        for (; b>0; --b){ int h=hist[b]; if (c+h >= krem) break; c+=h; }
        s_prefix = prefix | ((unsigned)b << shift);
        s_krem = krem - c;
      }
      __syncthreads();
      prefix = s_prefix; krem = s_krem;
      __syncthreads();
    }
    unsigned thr = prefix;
    const int per = 10;
    int base = tid*per;
    int cnt = 0;
    for (int i=base; i<base+per && i<N_NODES; ++i)
      if (__float_as_uint(kap[i])==thr) cnt++;
    sbuf[tid]=cnt; __syncthreads();
    for (int off=1; off<1024; off<<=1){
      int t = (tid>=off)? sbuf[tid-off] : 0;
      __syncthreads();
      sbuf[tid] += t;
      __syncthreads();
    }
    int taken = sbuf[tid] - cnt;
    for (int i=base; i<base+per && i<N_NODES; ++i) {
      unsigned b = __float_as_uint(kap[i]);
      int sel;
      if (b > thr) sel = 1;
      else if (b == thr) { sel = (taken < krem) ? 1 : 0; taken++; }
      else sel = 0;
      mask[i] = sel;
    }
  } else {
    int run = 0;
    for (int chunk=0; chunk<10; ++chunk) {
      int i = chunk*1024 + tid;
      int v = (i<N_NODES)? counts[i] : 0;
      sbuf[tid]=v; __syncthreads();
      for (int off=1; off<1024; off<<=1){
        int t = (tid>=off)? sbuf[tid-off]:0;
        __syncthreads();
        sbuf[tid]+=t;
        __syncthreads();
      }
      if (i<N_NODES) offs[i+1] = run + sbuf[tid];
      run += sbuf[1023];
      __syncthreads();
    }
    if (tid==0) offs[0]=0;
  }
}

// ---------------- fused: wh2 + per-edge weight + gamma/delta_f + CSR fill ----------------
__global__ __launch_bounds__(256) void k_weights_csr(
  const double* __restrict__ wh_acc, const float* __restrict__ wb1,
  const float* __restrict__ wm2, const float* __restrict__ wb2,
  const float* __restrict__ w3, const float* __restrict__ wb3,
  const int* __restrict__ ei, const int* __restrict__ eattr,
  const float* __restrict__ nev, const float* __restrict__ fv,
  const int* __restrict__ mask, const int* __restrict__ offs,
  const int* __restrict__ rank,
  float* __restrict__ weights, float* __restrict__ gamma, float* __restrict__ delta_f,
  int4* __restrict__ csr)
{
  __shared__ float h1[64], h2[64];
  int tid = threadIdx.x;
  if (tid < 64) h1[tid] = fmaxf((float)wh_acc[tid] + wb1[tid], 0.f);
  __syncthreads();
  if (tid < 64) {
    float a = wb2[tid];
    for (int k=0;k<64;++k) a = fmaf(h1[k], wm2[k*64+tid], a);
    h2[tid] = fmaxf(a, 0.f);
  }
  __syncthreads();
  int e = blockIdx.x*256 + tid;
  float ws = wb3[e];
  #pragma unroll 16
  for (int h=0; h<64; ++h) ws = fmaf(h2[h], w3[(size_t)h*N_EDGES + e], ws);
  float wt = sigmoidf_(ws);
  weights[e] = wt;
  int s = ei[e], d = ei[N_EDGES + e];
  float fd = fv[d] - fv[s];
  atomicAdd(&gamma[s], 0.5f*wt*fd*fd);
  atomicAdd(&delta_f[s], wt*fd);
  int a0 = eattr[e*3], a1 = eattr[e*3+1], a2 = eattr[e*3+2];
  float ew = nev[e];
  float mew = (mask[s] | mask[d]) ? 1e-5f : 1.0f;
  int4 rec;
  rec.x = s;
  rec.y = a0 | (a1<<8) | (a2<<16);
  rec.z = __float_as_int(ew);
  rec.w = __float_as_int(mew*ew);
  csr[offs[d] + rank[e]] = rec;
}

// ---------------- second curvature pass ----------------
__global__ __launch_bounds__(256) void k_edge2(
  const int* __restrict__ ei, const float* __restrict__ weights,
  const float* __restrict__ fv, const float* __restrict__ gamma,
  const float* __restrict__ delta_f,
  float* __restrict__ dg, float* __restrict__ gfd)
{
  int e = blockIdx.x*256 + threadIdx.x;
  int s = ei[e], d = ei[N_EDGES+e];
  float wt = weights[e];
  atomicAdd(&dg[s], wt*(gamma[d]-gamma[s]));
  float fd = fv[d]-fv[s];
  atomicAdd(&gfd[s], wt*fd*(delta_f[d]-delta_f[s]));
}

// ---------------- N x N curvature loss: grid (157 j-tiles, 8 i-tiles), partials ----------------
__global__ __launch_bounds__(256) void k_loss(
  const float* __restrict__ kap, const float* __restrict__ gamma,
  const float* __restrict__ dg, const float* __restrict__ gfd,
  double* __restrict__ lossparts)
{
  __shared__ float skap[1250];
  __shared__ double dred[256];
  int tid = threadIdx.x;
  int i0 = blockIdx.y*1250;
  for (int i=tid;i<1250;i+=256) skap[i]=kap[i0+i];
  __syncthreads();
  int lane = tid & 63, part = tid >> 6;
  int j = blockIdx.x*64 + lane;
  float g=0.f, g2=0.f;
  bool valid = j < N_NODES;
  if (valid){ g = gamma[j]; g2 = 0.5f*(dg[j]-gfd[j]); }
  float sum = 0.f;
  if (valid) {
    int a = part*313, b = a+313; if (b>1250) b=1250;
    for (int i=a;i<b;++i) sum += fmaxf(fmaf(skap[i], g, -g2), 0.f);
  }
  dred[tid] = (double)sum;
  __syncthreads();
  for (int off=128; off>0; off>>=1){
    if (tid<off) dred[tid]+=dred[tid+off];
    __syncthreads();
  }
  if (tid==0) lossparts[blockIdx.y*157 + blockIdx.x] = dred[0];
}

// ---------------- aggregation: LDS-staged records, fused input BN+relu ----------------
__global__ __launch_bounds__(256) void k_aggr(
  const float* __restrict__ hsrc, const double* __restrict__ statsPrev,
  const float* __restrict__ gPrev, const float* __restrict__ bPrev,
  const int4* __restrict__ csr, const int* __restrict__ offs,
  const float* __restrict__ bond_l, const float* __restrict__ nsl,
  const float* __restrict__ conv_eps, int l, int useW1,
  float* __restrict__ outP, double* __restrict__ stats_l)
{
  __shared__ float tab[3*16*DIM];       // 24 KB
  __shared__ float s_sc[DIM], s_sh[DIM];
  __shared__ int4 srec[4][64];          // 4 KB
  int tid = threadIdx.x;
  for (int i=tid; i<3*16*DIM; i+=256) tab[i] = bond_l[i];
  bool bn = (statsPrev != nullptr);
  if (bn && tid < DIM) {
    double m = statsPrev[tid] * (1.0/N_NODES);
    double v = statsPrev[DIM+tid] * (1.0/N_NODES) - m*m;
    float inv = (float)(1.0/sqrt(v + (double)BNEPS));
    float sc = gPrev[tid]*inv;
    s_sc[tid]=sc; s_sh[tid]=bPrev[tid]-(float)m*sc;
  }
  if (blockIdx.x == 0) {
    for (int i=tid; i<512; i+=256) stats_l[i] = 0.0;
  }
  __syncthreads();
  int wid = tid>>6, lane = tid&63;
  int n = blockIdx.x*4 + wid;
  float scx=1.f, scy=1.f, shx=0.f, shy=0.f;
  if (bn){ scx=s_sc[lane*2]; scy=s_sc[lane*2+1]; shx=s_sh[lane*2]; shy=s_sh[lane*2+1]; }
  float2 h0 = *(const float2*)(hsrc + (size_t)n*DIM + lane*2);
  if (bn){ h0.x = fmaxf(fmaf(h0.x,scx,shx),0.f); h0.y = fmaxf(fmaf(h0.y,scy,shy),0.f); }
  float c = conv_eps[l] * nsl[n];
  float ax = c*h0.x, ay = c*h0.y;
  int beg = offs[n], end = offs[n+1];
  for (int j0=beg; j0<end; j0+=64) {
    int m = end - j0; if (m>64) m=64;
    if (lane < m) srec[wid][lane] = csr[j0+lane];   // ds_write_b128, wave-local
    #pragma unroll 4
    for (int t=0;t<m;++t) {
      int4 r = srec[wid][t];                        // broadcast ds_read_b128
      float wt = __int_as_float(useW1 ? r.w : r.z);
      float2 hs = *(const float2*)(hsrc + (size_t)r.x*DIM + lane*2);
      if (bn){ hs.x = fmaxf(fmaf(hs.x,scx,shx),0.f); hs.y = fmaxf(fmaf(hs.y,scy,shy),0.f); }
      int a0 = r.y&255, a1=(r.y>>8)&255, a2=(r.y>>16)&255;
      float2 e0 = *(const float2*)(tab + a0*DIM + lane*2);
      float2 e1 = *(const float2*)(tab + 16*DIM + a1*DIM + lane*2);
      float2 e2 = *(const float2*)(tab + 32*DIM + a2*DIM + lane*2);
      float vx = hs.x + e0.x + e1.x + e2.x;
      float vy = hs.y + e0.y + e1.y + e2.y;
      ax = fmaf(wt, fmaxf(vx,0.f), ax);
      ay = fmaf(wt, fmaxf(vy,0.f), ay);
    }
  }
  float2 o; o.x=ax; o.y=ay;
  *(float2*)(outP + (size_t)n*DIM + lane*2) = o;
}

// ---------------- 64x64-tile GEMM, optional fused BN+relu on input, stats epilogue ----------------
__global__ __launch_bounds__(256) void k_gemm(
  const float* __restrict__ A, const float* __restrict__ W,
  const float* __restrict__ bias, float* __restrict__ Out,
  const double* __restrict__ statsIn, const float* __restrict__ gin, const float* __restrict__ bin,
  double* __restrict__ statsOut, int useBnIn)
{
  __shared__ __align__(16) float As[DIM*68];   // As[k*68 + r], transposed, padded
  __shared__ __align__(16) float Ws[DIM*64];   // Ws[k*64 + c]
  __shared__ float s_scale[DIM], s_shift[DIM];
  int tid = threadIdx.x;
  int r0 = blockIdx.x*64, c0 = blockIdx.y*64;
  if (useBnIn) {
    if (tid < DIM) {
      double m = statsIn[tid] * (1.0/N_NODES);
      double v = statsIn[DIM+tid] * (1.0/N_NODES) - m*m;
      float inv = (float)(1.0 / sqrt(v + (double)BNEPS));
      float sc = gin[tid]*inv;
      s_scale[tid] = sc;
      s_shift[tid] = bin[tid] - (float)m*sc;
    }
    __syncthreads();
  }
  for (int i=tid; i<2048; i+=256) {
    int k = i>>4, c4 = i&15;
    *(float4*)(&Ws[k*64 + c4*4]) = *(const float4*)(W + k*DIM + c0 + c4*4);
  }
  for (int i=tid; i<2048; i+=256) {
    int r = i&63, k4 = i>>6;
    int row = r0 + r;
    float4 v;
    if (row < N_NODES) v = *(const float4*)(A + (size_t)row*DIM + k4*4);
    else { v.x=0.f;v.y=0.f;v.z=0.f;v.w=0.f; }
    if (useBnIn) {
      int k = k4*4;
      v.x = fmaxf(fmaf(v.x, s_scale[k+0], s_shift[k+0]), 0.f);
      v.y = fmaxf(fmaf(v.y, s_scale[k+1], s_shift[k+1]), 0.f);
      v.z = fmaxf(fmaf(v.z, s_scale[k+2], s_shift[k+2]), 0.f);
      v.w = fmaxf(fmaf(v.w, s_scale[k+3], s_shift[k+3]), 0.f);
    }
    As[(k4*4+0)*68 + r] = v.x;
    As[(k4*4+1)*68 + r] = v.y;
    As[(k4*4+2)*68 + r] = v.z;
    As[(k4*4+3)*68 + r] = v.w;
  }
  __syncthreads();
  int tc = tid & 15, tr = tid >> 4;
  float acc[4][4];
  #pragma unroll
  for (int i=0;i<4;++i){ acc[i][0]=0.f; acc[i][1]=0.f; acc[i][2]=0.f; acc[i][3]=0.f; }
  #pragma unroll 4
  for (int k=0;k<DIM;++k) {
    float4 a4 = *(const float4*)(&As[k*68 + tr*4]);
    float4 w4 = *(const float4*)(&Ws[k*64 + tc*4]);
    acc[0][0]=fmaf(a4.x,w4.x,acc[0][0]); acc[0][1]=fmaf(a4.x,w4.y,acc[0][1]);
    acc[0][2]=fmaf(a4.x,w4.z,acc[0][2]); acc[0][3]=fmaf(a4.x,w4.w,acc[0][3]);
    acc[1][0]=fmaf(a4.y,w4.x,acc[1][0]); acc[1][1]=fmaf(a4.y,w4.y,acc[1][1]);
    acc[1][2]=fmaf(a4.y,w4.z,acc[1][2]); acc[1][3]=fmaf(a4.y,w4.w,acc[1][3]);
    acc[2][0]=fmaf(a4.z,w4.x,acc[2][0]); acc[2][1]=fmaf(a4.z,w4.y,acc[2][1]);
    acc[2][2]=fmaf(a4.z,w4.z,acc[2][2]); acc[2][3]=fmaf(a4.z,w4.w,acc[2][3]);
    acc[3][0]=fmaf(a4.w,w4.x,acc[3][0]); acc[3][1]=fmaf(a4.w,w4.y,acc[3][1]);
    acc[3][2]=fmaf(a4.w,w4.z,acc[3][2]); acc[3][3]=fmaf(a4.w,w4.w,acc[3][3]);
  }
  __syncthreads();
  float4 b4 = *(const float4*)(bias + c0 + tc*4);
  float ss[4]={0.f,0.f,0.f,0.f}, qq[4]={0.f,0.f,0.f,0.f};
  #pragma unroll
  for (int i=0;i<4;++i) {
    int row = r0 + tr*4 + i;
    if (row < N_NODES) {
      float o0=acc[i][0]+b4.x, o1=acc[i][1]+b4.y, o2=acc[i][2]+b4.z, o3=acc[i][3]+b4.w;
      float4 ov; ov.x=o0; ov.y=o1; ov.z=o2; ov.w=o3;
      *(float4*)(Out + (size_t)row*DIM + c0 + tc*4) = ov;
      ss[0]+=o0; ss[1]+=o1; ss[2]+=o2; ss[3]+=o3;
      qq[0]+=o0*o0; qq[1]+=o1*o1; qq[2]+=o2*o2; qq[3]+=o3*o3;
    }
  }
  float* rs = Ws;
  float* rq = Ws + 1024;
  #pragma unroll
  for (int j=0;j<4;++j){ rs[tr*64 + tc*4+j]=ss[j]; rq[tr*64 + tc*4+j]=qq[j]; }
  __syncthreads();
  if (tid < 64) {
    float s=0.f, q=0.f;
    #pragma unroll
    for (int t=0;t<16;++t){ s += rs[t*64+tid]; q += rq[t*64+tid]; }
    atomicAdd(&statsOut[c0+tid],       (double)s);
    atomicAdd(&statsOut[DIM+c0+tid],   (double)q);
  }
}

// ---------------- final: block 0 reduces loss; blocks 1.. do node_rep ----------------
__global__ __launch_bounds__(256) void k_final(
  const float* __restrict__ x,
  const float* __restrict__ t0, const float* __restrict__ t1, const float* __restrict__ t2,
  const float* __restrict__ t3, const float* __restrict__ t4,
  const double* __restrict__ stats, const float* __restrict__ bn_g, const float* __restrict__ bn_b,
  const double* __restrict__ lossparts, const float* __restrict__ kapparts,
  float* __restrict__ out)
{
  int tid = threadIdx.x;
  if (blockIdx.x == 0) {
    __shared__ double red[256];
    double acc = 0.0;
    for (int i=tid; i<1256; i+=256) acc += lossparts[i];
    for (int i=tid; i<2500; i+=256) acc -= (double)kapparts[i];
    red[tid] = acc;
    __syncthreads();
    for (int off=128; off>0; off>>=1){
      if (tid<off) red[tid]+=red[tid+off];
      __syncthreads();
    }
    if (tid==0) out[N_NODES*DIM] = (float)red[0];
    return;
  }
  __shared__ float sc[5][DIM], sh[5][DIM];
  if (tid < DIM) {
    for (int l=0;l<5;++l) {
      const double* st = stats + (size_t)l*512 + 256;
      double m = st[tid]*(1.0/N_NODES);
      double v = st[DIM+tid]*(1.0/N_NODES) - m*m;
      float inv = (float)(1.0/sqrt(v + (double)BNEPS));
      float s = bn_g[l*DIM+tid]*inv;
      sc[l][tid]=s; sh[l][tid]=bn_b[l*DIM+tid]-(float)m*s;
    }
  }
  __syncthreads();
  const float* ts[5] = {t0,t1,t2,t3,t4};
  int total = N_NODES*32;
  int stride = (gridDim.x-1)*256;
  for (int i = (blockIdx.x-1)*256 + tid; i < total; i += stride) {
    int c = (i & 31)*4;
    float4 a = ((const float4*)x)[i];
    #pragma unroll
    for (int l=0;l<5;++l) {
      float4 v = ((const float4*)ts[l])[i];
      v.x = fmaf(v.x, sc[l][c+0], sh[l][c+0]);
      v.y = fmaf(v.y, sc[l][c+1], sh[l][c+1]);
      v.z = fmaf(v.z, sc[l][c+2], sh[l][c+2]);
      v.w = fmaf(v.w, sc[l][c+3], sh[l][c+3]);
      if (l < 4) { v.x=fmaxf(v.x,0.f); v.y=fmaxf(v.y,0.f); v.z=fmaxf(v.z,0.f); v.w=fmaxf(v.w,0.f); }
      a.x+=v.x; a.y+=v.y; a.z+=v.z; a.w+=v.w;
    }
    ((float4*)out)[i] = a;
  }
}

extern "C" void kernel_launch(void* const* d_in, const int* in_sizes, int n_in,
                              void* d_out, int out_size, void* d_ws, size_t ws_size,
                              hipStream_t stream)
{
  const int*   x_feat   = (const int*)d_in[0];
  const int*   eidx     = (const int*)d_in[1];
  const int*   eattr    = (const int*)d_in[2];
  const float* nev      = (const float*)d_in[3];
  const float* nsl      = (const float*)d_in[4];
  const float* atom_emb = (const float*)d_in[5];
  const float* cw1 = (const float*)d_in[6];
  const float* cb1 = (const float*)d_in[7];
  const float* cw2 = (const float*)d_in[8];
  const float* cb2 = (const float*)d_in[9];
  const float* fw1 = (const float*)d_in[10];
  const float* fb1 = (const float*)d_in[11];
  const float* fw2 = (const float*)d_in[12];
  const float* fb2 = (const float*)d_in[13];
  const float* wm1 = (const float*)d_in[14];
  const float* wb1 = (const float*)d_in[15];
  const float* wm2 = (const float*)d_in[16];
  const float* wb2 = (const float*)d_in[17];
  const float* wm3 = (const float*)d_in[18];
  const float* wb3 = (const float*)d_in[19];
  const float* bond = (const float*)d_in[20];
  const float* conv_w1 = (const float*)d_in[21];
  const float* conv_b1 = (const float*)d_in[22];
  const float* conv_bn_g = (const float*)d_in[23];
  const float* conv_bn_b = (const float*)d_in[24];
  const float* conv_w2 = (const float*)d_in[25];
  const float* conv_b2 = (const float*)d_in[26];
  const float* conv_eps = (const float*)d_in[27];
  const float* bn_g = (const float*)d_in[28];
  const float* bn_b = (const float*)d_in[29];
  float* out = (float*)d_out;

  char* ws = (char*)d_ws;
  size_t off = 0;
  auto alloc = [&](size_t bytes)->char* {
    char* p = ws + off;
    off += (bytes + 255) & ~(size_t)255;
    return p;
  };
  float* hA       = (float*)alloc((size_t)N_NODES*DIM*4);
  float* bufP     = (float*)alloc((size_t)N_NODES*DIM*4);
  float* bufQ     = (float*)alloc((size_t)N_NODES*DIM*4);
  float* t2b[NLAYERS];
  for (int l=0;l<NLAYERS;++l) t2b[l] = (float*)alloc((size_t)N_NODES*DIM*4);
  int4*  csr      = (int4*)alloc((size_t)N_EDGES*16);
  float* weights  = (float*)alloc((size_t)N_EDGES*4);
  int*   rank     = (int*)alloc((size_t)N_EDGES*4);
  int*   counts   = (int*)alloc((size_t)N_NODES*4);
  int*   offs     = (int*)alloc((size_t)(N_NODES+1)*4);
  float* kap      = (float*)alloc((size_t)N_NODES*4);
  float* fv       = (float*)alloc((size_t)N_NODES*4);
  float* gamma    = (float*)alloc((size_t)N_NODES*4);
  float* delta_f  = (float*)alloc((size_t)N_NODES*4);
  float* dg       = (float*)alloc((size_t)N_NODES*4);
  float* gfd      = (float*)alloc((size_t)N_NODES*4);
  int*   mask     = (int*)alloc((size_t)N_NODES*4);
  double* wh_acc  = (double*)alloc(64*8);
  float* kapparts = (float*)alloc(2500*4);
  double* lossparts = (double*)alloc(1256*8);
  double* stats   = (double*)alloc((size_t)NLAYERS*512*8);

  k_node<<<N_NODES/4, 256, 0, stream>>>(x_feat, atom_emb, cw1,cb1,cw2,cb2, fw1,fb1,fw2,fb2,
                                        hA, kap, fv, kapparts,
                                        counts, gamma, delta_f, dg, gfd, wh_acc);
  k_edge_pre<<<N_EDGES/256, 256, 0, stream>>>(eidx, eattr, wm1, counts, rank, wh_acc);
  k_topk_scan<<<2, 1024, 0, stream>>>(kap, mask, counts, offs);
  k_weights_csr<<<N_EDGES/256, 256, 0, stream>>>(wh_acc, wb1, wm2, wb2, wm3, wb3,
                                                 eidx, eattr, nev, fv, mask, offs, rank,
                                                 weights, gamma, delta_f, csr);
  k_edge2<<<N_EDGES/256, 256, 0, stream>>>(eidx, weights, fv, gamma, delta_f, dg, gfd);
  k_loss<<<dim3((N_NODES+63)/64, 8), 256, 0, stream>>>(kap, gamma, dg, gfd, lossparts);

  for (int l=0; l<NLAYERS; ++l) {
    double* stats_l = stats + (size_t)l*512;
    const float* hsrc = (l==0) ? hA : t2b[l-1];
    const double* statsPrev = (l==0) ? nullptr : (stats + (size_t)(l-1)*512 + 256);
    const float* gPrev = bn_g + (size_t)(l>0?l-1:0)*DIM;
    const float* bPrev = bn_b + (size_t)(l>0?l-1:0)*DIM;
    k_aggr<<<N_NODES/4, 256, 0, stream>>>(hsrc, statsPrev, gPrev, bPrev, csr, offs,
                                          bond + (size_t)l*3*16*DIM, nsl, conv_eps, l,
                                          (l>0)?1:0, bufP, stats_l);
    k_gemm<<<dim3((N_NODES+63)/64, 2), 256, 0, stream>>>(bufP, conv_w1 + (size_t)l*DIM*DIM,
                conv_b1 + l*DIM, bufQ,
                (const double*)nullptr, (const float*)nullptr, (const float*)nullptr,
                stats_l, 0);
    k_gemm<<<dim3((N_NODES+63)/64, 2), 256, 0, stream>>>(bufQ, conv_w2 + (size_t)l*DIM*DIM,
                conv_b2 + l*DIM, t2b[l],
                stats_l, conv_bn_g + l*DIM, conv_bn_b + l*DIM,
                stats_l + 256, 1);
  }
  k_final<<<1025, 256, 0, stream>>>(hA, t2b[0], t2b[1], t2b[2], t2b[3], t2b[4],
                                    stats, bn_g, bn_b, lossparts, kapparts, out);
}